// Round 8
// baseline (181.407 us; speedup 1.0000x reference)
//
#include <hip/hip_runtime.h>
#include <math.h>

#define NN 648      // code length / variables
#define EE 1944     // edges
#define NCHK 324    // checks, each = 6 consecutive edges
#define BATCH 2048
#define BS 256      // extraction kernels
#define BSM 384     // bp_main: one check per thread (324 < 384), 6 waves
#define TL_CLAMP 14.508648f   // 2*atanh(0.999999)

// ---------------------------------------------------------------------------
// Fast transcendentals (hardware v_exp_f32 / v_log_f32 / v_rcp_f32).
// CRITICAL: tanh_half returns 0 IFF x==0 — zero-ness gates the reference's
// cn_update nz-mask semantics (R2 lesson: exp path flushes |x|<~2e-7 -> Taylor
// small path keeps tiny nonzeros nonzero).
// ---------------------------------------------------------------------------
__device__ __forceinline__ float rcp_fast(float x) { return __builtin_amdgcn_rcpf(x); }

__device__ __forceinline__ float tanh_half(float x) {
    // tanh(x/2) = 1 - 2/(e^x + 1): sign-correct, saturates exactly to +/-1.
    float E = __expf(x);
    float big = 1.0f - 2.0f * rcp_fast(E + 1.0f);
    float u = 0.5f * x;
    float small = u * (1.0f - 0.33333334f * u * u);   // |u|<=2^-6, err ~6e-10
    return (fabsf(x) < 0.03125f) ? small : big;
}

__device__ __forceinline__ float sigm(float s) {
    return rcp_fast(1.0f + __expf(-s));
}

// Two-log CN form: ext = Q/a, 2*atanh(ext) = ln2*(log2|a+Q| - log2|a-Q|),
// clamped at +/-2*atanh(0.999999). a-+Q==0 -> +/-inf -> clamp (== ref clamp).
__device__ __forceinline__ float cn_edge(float a, float Q) {
    float t = 0.6931472f * (__log2f(fabsf(a + Q)) - __log2f(fabsf(a - Q)));
    return fminf(fmaxf(t, -TL_CLAMP), TL_CLAMP);
}

// Rare path (exact-zero member / full underflow): reference skip-zero / any_nz
// extrinsic semantics.
__device__ __noinline__ float cn_fallback(float a, float t0, float t1, float t2,
                                          float t3, float t4, float t5) {
    float vv[6] = {t0, t1, t2, t3, t4, t5};
    float P = 1.0f; int cz = 0;
    #pragma unroll
    for (int k = 0; k < 6; k++) {
        if (vv[k] == 0.0f) cz++; else P *= vv[k];
    }
    float ext;
    if (a != 0.0f) ext = (cz >= 5) ? 0.0f : P * rcp_fast(a);
    else           ext = (cz >= 6) ? 0.0f : P;
    ext = fminf(fmaxf(ext, -0.999999f), 0.999999f);
    return 0.6931472f * __log2f((1.0f + ext) * rcp_fast(1.0f - ext));
}

// ---------------------------------------------------------------------------
// Structure extraction (re-run every call; inputs restored pristine each time)
// M_out is [N,E] = M_ev.T: one nonzero (==1.0) per column e, at row var_of[e].
// Each var appears once per permutation layer (layer = e/NN) -> race-free.
// ---------------------------------------------------------------------------
__global__ __launch_bounds__(BS) void extract_struct(
    const float4* __restrict__ M_out4,
    int* __restrict__ var_of, int* __restrict__ varEdge,
    unsigned short* __restrict__ varc16) {
    int t = blockIdx.x * BS + threadIdx.x;
    if (t >= NN * EE / 4) return;
    float4 v = M_out4[t];
    int flat = t * 4;
    int n = flat / EE;
    int e = flat - n * EE;
    if (v.x != 0.0f) { var_of[e]     = n; varEdge[n*3 + (e)    /NN] = e;     varc16[e]     = (unsigned short)n; }
    if (v.y != 0.0f) { var_of[e + 1] = n; varEdge[n*3 + (e + 1)/NN] = e + 1; varc16[e + 1] = (unsigned short)n; }
    if (v.z != 0.0f) { var_of[e + 2] = n; varEdge[n*3 + (e + 2)/NN] = e + 2; varc16[e + 2] = (unsigned short)n; }
    if (v.w != 0.0f) { var_of[e + 3] = n; varEdge[n*3 + (e + 3)/NN] = e + 3; varc16[e + 3] = (unsigned short)n; }
}

// One thread per (matrix, edge): 2 scalar loads each, plus NN threads for W9.
// Weight layout per CHECK: 12 floats (2 per edge) = 3 float4 (float2-index
// == e, since edges are check-consecutive). nb packed as (eb<<16)|ea.
__global__ __launch_bounds__(BS) void extract_weights(
    const float* __restrict__ W1, const float* __restrict__ W3,
    const float* __restrict__ W5, const float* __restrict__ W7,
    const float* __restrict__ W9,
    const int* __restrict__ var_of, const int* __restrict__ varEdge,
    unsigned* __restrict__ nb6,
    float4* __restrict__ w1q, float4* __restrict__ w3q,
    float4* __restrict__ w5q, float4* __restrict__ w7q,
    float* __restrict__ w9v) {
    int t = blockIdx.x * BS + threadIdx.x;
    if (t < 4 * EE) {
        int m = t / EE;
        int e = t - m * EE;
        int n = var_of[e];
        int e0 = varEdge[3 * n], e1 = varEdge[3 * n + 1], e2 = varEdge[3 * n + 2];
        int ea, eb;
        if (e == e0)      { ea = e1; eb = e2; }
        else if (e == e1) { ea = e0; eb = e2; }
        else              { ea = e0; eb = e1; }
        const float* W = (m == 0) ? W1 : (m == 1) ? W3 : (m == 2) ? W5 : W7;
        size_t row = (size_t)e * EE;
        float2 w = make_float2(W[row + ea], W[row + eb]);
        float4* dq = (m == 0) ? w1q : (m == 1) ? w3q : (m == 2) ? w5q : w7q;
        ((float2*)dq)[e] = w;
        if (m == 0) nb6[e] = (unsigned)ea | ((unsigned)eb << 16);
    } else if (t < 4 * EE + NN) {
        int n = t - 4 * EE;
        #pragma unroll
        for (int k = 0; k < 3; k++) {
            int e = varEdge[3 * n + k];
            w9v[3 * n + k] = W9[(size_t)n * EE + e];
        }
    }
}

// ---------------------------------------------------------------------------
// Main BP kernel (R6 shape — best known: 2048 blocks, 1 row/block, 5 blocks/CU
// = 30 waves/CU): one check per thread, te in registers, tl double-buffered,
// 1 barrier per layer. R8 deltas: neighbor offsets unpacked once to registers;
// next-layer weights prefetched before cn_store so the barrier's vmcnt(0)
// drain absorbs their latency; marg llr/W9 coefficients register-cached.
// ---------------------------------------------------------------------------
__global__ __launch_bounds__(BSM, 8) void bp_main(
    const float* __restrict__ x,
    const unsigned* __restrict__ varc,   // ushort[EE] viewed as uint[EE/2]
    const unsigned* __restrict__ nb6,    // uint[EE]: (eb<<16)|ea
    const int* __restrict__ varEdge,     // [3*NN]
    const float4* __restrict__ w1q, const float4* __restrict__ w3q,
    const float4* __restrict__ w5q, const float4* __restrict__ w7q,
    const float* __restrict__ w9v,
    float* __restrict__ out) {
    __shared__ __align__(16) float llr_s[NN];
    __shared__ __align__(16) float tlA[EE];
    __shared__ __align__(16) float tlB[EE];
    const int b = blockIdx.x;
    const int tid = threadIdx.x;

    // llr load: 324 float2, one iter (threads >= 324 idle here)
    {
        const float2* xr2 = (const float2*)(x + (size_t)b * NN);
        if (tid < NN / 2) ((float2*)llr_s)[tid] = xr2[tid];
    }

    // marg-out state cached in registers at init (reused every marg + epilogue)
    int m0[2], m1[2], m2[2];
    float a9[2][3];
    #pragma unroll
    for (int j = 0; j < 2; j++) {
        int n = tid + j * BSM;
        if (n < NN) {
            m0[j] = varEdge[3 * n]; m1[j] = varEdge[3 * n + 1];
            m2[j] = varEdge[3 * n + 2];
            a9[j][0] = w9v[3 * n]; a9[j][1] = w9v[3 * n + 1];
            a9[j][2] = w9v[3 * n + 2];
        } else {
            m0[j] = m1[j] = m2[j] = 0;
            a9[j][0] = a9[j][1] = a9[j][2] = 0.f;
        }
    }
    __syncthreads();

    const bool ck = tid < NCHK;
    const int c = tid;
    float lb[6];        // llr at this check's 6 variables (loop-invariant)
    int oa[6], ob[6];   // unpacked neighbor tl indices (registers, once)
    float te[6];        // check members — registers, never LDS
    float llr_m[2];     // llr at marg vars (registers)
    float4 wa, wb, wc;  // current layer's 12 weights (prefetched)

    #pragma unroll
    for (int j = 0; j < 2; j++) {
        int n = tid + j * BSM;
        llr_m[j] = (n < NN) ? llr_s[n] : 0.f;
    }
    if (ck) {
        #pragma unroll
        for (int j = 0; j < 3; j++) {
            unsigned vv = varc[3 * c + j];
            lb[2 * j]     = llr_s[vv & 0xffffu];
            lb[2 * j + 1] = llr_s[vv >> 16];
        }
        #pragma unroll
        for (int j = 0; j < 6; j++) {
            unsigned p = nb6[6 * c + j];
            oa[j] = p & 0xffffu; ob[j] = p >> 16;
            te[j] = tanh_half(lb[j]);   // iter 0: te = tanh(0.5*llr[var])
        }
        // prefetch L=0 weights; latency hidden behind CN0 logs + barrier
        wa = w1q[3 * c]; wb = w1q[3 * c + 1]; wc = w1q[3 * c + 2];
    }

    auto cn_store = [&](float* dst) {
        float Q = ((te[0] * te[1]) * (te[2] * te[3])) * (te[4] * te[5]);
        float2* d = (float2*)(dst + 6 * c);        // 24c bytes: 8-aligned
        if (__builtin_expect(Q != 0.0f, 1)) {
            d[0] = make_float2(cn_edge(te[0], Q), cn_edge(te[1], Q));
            d[1] = make_float2(cn_edge(te[2], Q), cn_edge(te[3], Q));
            d[2] = make_float2(cn_edge(te[4], Q), cn_edge(te[5], Q));
        } else {
            float r[6];
            #pragma unroll
            for (int j = 0; j < 6; j++)
                r[j] = cn_fallback(te[j], te[0], te[1], te[2], te[3], te[4], te[5]);
            d[0] = make_float2(r[0], r[1]);
            d[1] = make_float2(r[2], r[3]);
            d[2] = make_float2(r[4], r[5]);
        }
    };
    auto marg = [&](const float* tl, float* dst) {
        #pragma unroll
        for (int j = 0; j < 2; j++) {
            int n = tid + j * BSM;
            if (n < NN)
                dst[n] = sigm(llr_m[j] + tl[m0[j]] + tl[m1[j]] + tl[m2[j]]);
        }
    };

    if (ck) cn_store(tlA);
    __syncthreads();
    // out1 -> chunk 4 (return order: out5,out4,out3,out2,out1)
    marg(tlA, out + ((size_t)(4 * BATCH) + b) * NN);

    const float4* wqs[4] = {w1q, w3q, w5q, w7q};
    #pragma unroll
    for (int L = 0; L < 4; L++) {
        const float* tlc = (L & 1) ? tlB : tlA;   // CN_{L-1} output
        float* tln = (L & 1) ? tlA : tlB;         // CN_L output
        if (ck) {
            // VN: pre = w0*tl[ea] + w1*tl[eb] + llr[var]; te = tanh(pre/2)
            te[0] = tanh_half(fmaf(wa.x, tlc[oa[0]], fmaf(wa.y, tlc[ob[0]], lb[0])));
            te[1] = tanh_half(fmaf(wa.z, tlc[oa[1]], fmaf(wa.w, tlc[ob[1]], lb[1])));
            te[2] = tanh_half(fmaf(wb.x, tlc[oa[2]], fmaf(wb.y, tlc[ob[2]], lb[2])));
            te[3] = tanh_half(fmaf(wb.z, tlc[oa[3]], fmaf(wb.w, tlc[ob[3]], lb[3])));
            te[4] = tanh_half(fmaf(wc.x, tlc[oa[4]], fmaf(wc.y, tlc[ob[4]], lb[4])));
            te[5] = tanh_half(fmaf(wc.z, tlc[oa[5]], fmaf(wc.w, tlc[ob[5]], lb[5])));
            // prefetch NEXT layer's weights: issue now, drained by the barrier
            if (L < 3) {
                const float4* wn = wqs[L + 1];
                wa = wn[3 * c]; wb = wn[3 * c + 1]; wc = wn[3 * c + 2];
            }
            cn_store(tln);   // buffer nobody reads until next barrier
        }
        __syncthreads();
        if (L < 3) {
            // out2->chunk3, out3->chunk2, out4->chunk1
            marg(tln, out + ((size_t)((3 - L) * BATCH) + b) * NN);
        } else {
            // out5 -> chunk 0: sigmoid(t@W9.T + llr)   (B4 = I)
            #pragma unroll
            for (int j = 0; j < 2; j++) {
                int n = tid + j * BSM;
                if (n < NN) {
                    float s = llr_m[j] + a9[j][0] * tln[m0[j]]
                            + a9[j][1] * tln[m1[j]] + a9[j][2] * tln[m2[j]];
                    out[(size_t)b * NN + n] = sigm(s);
                }
            }
        }
    }
}

// ---------------------------------------------------------------------------
extern "C" void kernel_launch(void* const* d_in, const int* in_sizes, int n_in,
                              void* d_out, int out_size, void* d_ws, size_t ws_size,
                              hipStream_t stream) {
    const float* x     = (const float*)d_in[0];
    const float* M_out = (const float*)d_in[3];
    const float* W1    = (const float*)d_in[5];
    const float* W3    = (const float*)d_in[6];
    const float* W5    = (const float*)d_in[7];
    const float* W7    = (const float*)d_in[8];
    const float* W9    = (const float*)d_in[9];
    // d_in[1]=M_first, d_in[2]=M_cn (patterns implied by check structure),
    // d_in[4]=bias_matrix (values 1.0), d_in[10..14]=B0..B4 (identity).
    float* out = (float*)d_out;

    char* ws = (char*)d_ws;                    // 16B-aligned base
    float4* w1q     = (float4*)ws;         ws += (EE / 2) * 16;
    float4* w3q     = (float4*)ws;         ws += (EE / 2) * 16;
    float4* w5q     = (float4*)ws;         ws += (EE / 2) * 16;
    float4* w7q     = (float4*)ws;         ws += (EE / 2) * 16;
    int*    var_of  = (int*)ws;            ws += EE * 4;
    int*    varEdge = (int*)ws;            ws += NN * 3 * 4;
    float*  w9v     = (float*)ws;          ws += NN * 3 * 4;
    unsigned* nb6   = (unsigned*)ws;       ws += EE * 4;
    unsigned short* varc16 = (unsigned short*)ws; ws += EE * 2;

    const int tot4 = NN * EE / 4;
    extract_struct<<<(tot4 + BS - 1) / BS, BS, 0, stream>>>(
        (const float4*)M_out, var_of, varEdge, varc16);
    const int totW = 4 * EE + NN;
    extract_weights<<<(totW + BS - 1) / BS, BS, 0, stream>>>(
        W1, W3, W5, W7, W9, var_of, varEdge, nb6, w1q, w3q, w5q, w7q, w9v);
    bp_main<<<BATCH, BSM, 0, stream>>>(
        x, (const unsigned*)varc16, nb6, varEdge, w1q, w3q, w5q, w7q, w9v, out);
}

// Round 9
// 166.412 us; speedup vs baseline: 1.0901x; 1.0901x over previous
//
#include <hip/hip_runtime.h>
#include <math.h>

#define NN 648      // code length / variables
#define EE 1944     // edges
#define NCHK 324    // checks, each = 6 consecutive edges
#define EEP (7 * NCHK)   // padded tl size: stride 7 per check (bank-conflict fix)
#define BATCH 2048
#define BS 256      // extraction kernels
#define BSM 384     // bp_main: one check per thread (324 < 384), 6 waves
#define TL_CLAMP 14.508648f   // 2*atanh(0.999999)

// ---------------------------------------------------------------------------
// Fast transcendentals (hardware v_exp_f32 / v_log_f32 / v_rcp_f32).
// CRITICAL: tanh_half returns 0 IFF x==0 — zero-ness gates the reference's
// cn_update nz-mask semantics (R2 lesson: exp path flushes |x|<~2e-7 -> Taylor
// small path keeps tiny nonzeros nonzero).
// ---------------------------------------------------------------------------
__device__ __forceinline__ float rcp_fast(float x) { return __builtin_amdgcn_rcpf(x); }

__device__ __forceinline__ float tanh_half(float x) {
    // tanh(x/2) = 1 - 2/(e^x + 1): sign-correct, saturates exactly to +/-1.
    float E = __expf(x);
    float big = 1.0f - 2.0f * rcp_fast(E + 1.0f);
    float u = 0.5f * x;
    float small = u * (1.0f - 0.33333334f * u * u);   // |u|<=2^-6, err ~6e-10
    return (fabsf(x) < 0.03125f) ? small : big;
}

__device__ __forceinline__ float sigm(float s) {
    return rcp_fast(1.0f + __expf(-s));
}

// Two-log CN form: ext = Q/a, 2*atanh(ext) = ln2*(log2|a+Q| - log2|a-Q|),
// clamped at +/-2*atanh(0.999999). a-+Q==0 -> +/-inf -> clamp (== ref clamp).
__device__ __forceinline__ float cn_edge(float a, float Q) {
    float t = 0.6931472f * (__log2f(fabsf(a + Q)) - __log2f(fabsf(a - Q)));
    return fminf(fmaxf(t, -TL_CLAMP), TL_CLAMP);
}

// Rare path (exact-zero member / full underflow): reference skip-zero / any_nz
// extrinsic semantics.
__device__ __noinline__ float cn_fallback(float a, float t0, float t1, float t2,
                                          float t3, float t4, float t5) {
    float vv[6] = {t0, t1, t2, t3, t4, t5};
    float P = 1.0f; int cz = 0;
    #pragma unroll
    for (int k = 0; k < 6; k++) {
        if (vv[k] == 0.0f) cz++; else P *= vv[k];
    }
    float ext;
    if (a != 0.0f) ext = (cz >= 5) ? 0.0f : P * rcp_fast(a);
    else           ext = (cz >= 6) ? 0.0f : P;
    ext = fminf(fmaxf(ext, -0.999999f), 0.999999f);
    return 0.6931472f * __log2f((1.0f + ext) * rcp_fast(1.0f - ext));
}

// padded tl index: edge e -> 7*(e/6) + e%6 == e + e/6
__device__ __forceinline__ int pad6(int e) { return e + (int)((unsigned)e / 6u); }

// ---------------------------------------------------------------------------
// Structure extraction (re-run every call; inputs restored pristine each time)
// M_out is [N,E] = M_ev.T: one nonzero (==1.0) per column e, at row var_of[e].
// Each var appears once per permutation layer (layer = e/NN) -> race-free.
// ---------------------------------------------------------------------------
__global__ __launch_bounds__(BS) void extract_struct(
    const float4* __restrict__ M_out4,
    int* __restrict__ var_of, int* __restrict__ varEdge,
    unsigned short* __restrict__ varc16) {
    int t = blockIdx.x * BS + threadIdx.x;
    if (t >= NN * EE / 4) return;
    float4 v = M_out4[t];
    int flat = t * 4;
    int n = flat / EE;
    int e = flat - n * EE;
    if (v.x != 0.0f) { var_of[e]     = n; varEdge[n*3 + (e)    /NN] = e;     varc16[e]     = (unsigned short)n; }
    if (v.y != 0.0f) { var_of[e + 1] = n; varEdge[n*3 + (e + 1)/NN] = e + 1; varc16[e + 1] = (unsigned short)n; }
    if (v.z != 0.0f) { var_of[e + 2] = n; varEdge[n*3 + (e + 2)/NN] = e + 2; varc16[e + 2] = (unsigned short)n; }
    if (v.w != 0.0f) { var_of[e + 3] = n; varEdge[n*3 + (e + 3)/NN] = e + 3; varc16[e + 3] = (unsigned short)n; }
}

// One thread per (matrix, edge): 2 scalar loads each, plus NN threads for W9.
// Weight layout per CHECK: 12 floats (2 per edge) = 3 float4 (float2-index
// == e, since edges are check-consecutive). nb packed as (padded eb<<16)|ea.
__global__ __launch_bounds__(BS) void extract_weights(
    const float* __restrict__ W1, const float* __restrict__ W3,
    const float* __restrict__ W5, const float* __restrict__ W7,
    const float* __restrict__ W9,
    const int* __restrict__ var_of, const int* __restrict__ varEdge,
    unsigned* __restrict__ nb6,
    float4* __restrict__ w1q, float4* __restrict__ w3q,
    float4* __restrict__ w5q, float4* __restrict__ w7q,
    float* __restrict__ w9v) {
    int t = blockIdx.x * BS + threadIdx.x;
    if (t < 4 * EE) {
        int m = t / EE;
        int e = t - m * EE;
        int n = var_of[e];
        int e0 = varEdge[3 * n], e1 = varEdge[3 * n + 1], e2 = varEdge[3 * n + 2];
        int ea, eb;
        if (e == e0)      { ea = e1; eb = e2; }
        else if (e == e1) { ea = e0; eb = e2; }
        else              { ea = e0; eb = e1; }
        const float* W = (m == 0) ? W1 : (m == 1) ? W3 : (m == 2) ? W5 : W7;
        size_t row = (size_t)e * EE;
        float2 w = make_float2(W[row + ea], W[row + eb]);
        float4* dq = (m == 0) ? w1q : (m == 1) ? w3q : (m == 2) ? w5q : w7q;
        ((float2*)dq)[e] = w;
        if (m == 0)
            nb6[e] = (unsigned)pad6(ea) | ((unsigned)pad6(eb) << 16);
    } else if (t < 4 * EE + NN) {
        int n = t - 4 * EE;
        #pragma unroll
        for (int k = 0; k < 3; k++) {
            int e = varEdge[3 * n + k];
            w9v[3 * n + k] = W9[(size_t)n * EE + e];
        }
    }
}

// ---------------------------------------------------------------------------
// Main BP kernel — R6 structure (best known: 2048 blocks, 1 row/block,
// 5 blocks/CU = 30 waves/CU; te in registers; tl double-buffered; 1 barrier
// per layer). R9 delta: tl padded to stride 7/check -> cn_store writes and
// structured gathers hit all 32 banks (2-way = free) instead of 16 (4-way).
// NO persistent register additions (R8 lesson: they spill -> scratch traffic).
// LDS: llr 2.6 KB + 2*tl 9.1 KB*... = 2*2268*4 + 648*4 = 20.7 KB -> still 5/CU.
// ---------------------------------------------------------------------------
__global__ __launch_bounds__(BSM, 8) void bp_main(
    const float* __restrict__ x,
    const unsigned* __restrict__ varc,   // ushort[EE] viewed as uint[EE/2]
    const unsigned* __restrict__ nb6,    // uint[EE]: (pad(eb)<<16)|pad(ea)
    const int* __restrict__ varEdge,     // [3*NN] raw edge ids
    const float4* __restrict__ w1q, const float4* __restrict__ w3q,
    const float4* __restrict__ w5q, const float4* __restrict__ w7q,
    const float* __restrict__ w9v,
    float* __restrict__ out) {
    __shared__ __align__(16) float llr_s[NN];
    __shared__ __align__(16) float tlA[EEP];
    __shared__ __align__(16) float tlB[EEP];
    const int b = blockIdx.x;
    const int tid = threadIdx.x;

    // llr load: 324 float2, one iter (threads >= 324 idle here)
    {
        const float2* xr2 = (const float2*)(x + (size_t)b * NN);
        if (tid < NN / 2) ((float2*)llr_s)[tid] = xr2[tid];
    }
    __syncthreads();

    const bool ck = tid < NCHK;
    const int c = tid;
    float lb[6];        // llr at this check's 6 variables (loop-invariant)
    unsigned nbp[6];    // packed PADDED extrinsic neighbor tl indices
    float te[6];        // check members — registers, never LDS

    if (ck) {
        #pragma unroll
        for (int j = 0; j < 3; j++) {
            unsigned vv = varc[3 * c + j];
            lb[2 * j]     = llr_s[vv & 0xffffu];
            lb[2 * j + 1] = llr_s[vv >> 16];
        }
        #pragma unroll
        for (int j = 0; j < 6; j++) {
            nbp[j] = nb6[6 * c + j];
            te[j] = tanh_half(lb[j]);   // iter 0: te = tanh(0.5*llr[var])
        }
    }
    // marg-out tl offsets (PADDED) cached; reused by W9 epilogue
    int m0[2], m1[2], m2[2];
    #pragma unroll
    for (int j = 0; j < 2; j++) {
        int n = tid + j * BSM;
        if (n < NN) {
            m0[j] = pad6(varEdge[3 * n]);
            m1[j] = pad6(varEdge[3 * n + 1]);
            m2[j] = pad6(varEdge[3 * n + 2]);
        } else { m0[j] = m1[j] = m2[j] = 0; }
    }

    auto cn_store = [&](float* dst) {
        float Q = ((te[0] * te[1]) * (te[2] * te[3])) * (te[4] * te[5]);
        float* d = dst + 7 * c;   // stride 7: banks 7c%32 cover all 32 -> free
        if (__builtin_expect(Q != 0.0f, 1)) {
            #pragma unroll
            for (int j = 0; j < 6; j++) d[j] = cn_edge(te[j], Q);
        } else {
            #pragma unroll
            for (int j = 0; j < 6; j++)
                d[j] = cn_fallback(te[j], te[0], te[1], te[2], te[3], te[4], te[5]);
        }
    };
    auto marg = [&](const float* tl, float* dst) {
        #pragma unroll
        for (int j = 0; j < 2; j++) {
            int n = tid + j * BSM;
            if (n < NN)
                dst[n] = sigm(llr_s[n] + tl[m0[j]] + tl[m1[j]] + tl[m2[j]]);
        }
    };

    if (ck) cn_store(tlA);
    __syncthreads();
    // out1 -> chunk 4 (return order: out5,out4,out3,out2,out1)
    marg(tlA, out + ((size_t)(4 * BATCH) + b) * NN);

    const float4* wqs[4] = {w1q, w3q, w5q, w7q};
    #pragma unroll
    for (int L = 0; L < 4; L++) {
        const float4* __restrict__ wq = wqs[L];
        const float* tlc = (L & 1) ? tlB : tlA;   // CN_{L-1} output
        float* tln = (L & 1) ? tlA : tlB;         // CN_L output
        if (ck) {
            // short-lived weight locals (R6 profile — no persistent prefetch)
            float4 wa = wq[3 * c], wb = wq[3 * c + 1], wc = wq[3 * c + 2];
            float w[12] = {wa.x, wa.y, wa.z, wa.w, wb.x, wb.y, wb.z, wb.w,
                           wc.x, wc.y, wc.z, wc.w};
            // VN: pre = w0*tl[ea] + w1*tl[eb] + llr[var]; te = tanh(pre/2)
            #pragma unroll
            for (int j = 0; j < 6; j++) {
                float pre = fmaf(w[2 * j], tlc[nbp[j] & 0xffffu],
                            fmaf(w[2 * j + 1], tlc[nbp[j] >> 16], lb[j]));
                te[j] = tanh_half(pre);
            }
            cn_store(tln);   // buffer nobody reads until next barrier
        }
        __syncthreads();
        if (L < 3) {
            // out2->chunk3, out3->chunk2, out4->chunk1
            marg(tln, out + ((size_t)((3 - L) * BATCH) + b) * NN);
        } else {
            // out5 -> chunk 0: sigmoid(t@W9.T + llr)   (B4 = I)
            #pragma unroll
            for (int j = 0; j < 2; j++) {
                int n = tid + j * BSM;
                if (n < NN) {
                    float s = llr_s[n]
                            + w9v[3 * n]     * tln[m0[j]]
                            + w9v[3 * n + 1] * tln[m1[j]]
                            + w9v[3 * n + 2] * tln[m2[j]];
                    out[(size_t)b * NN + n] = sigm(s);
                }
            }
        }
    }
}

// ---------------------------------------------------------------------------
extern "C" void kernel_launch(void* const* d_in, const int* in_sizes, int n_in,
                              void* d_out, int out_size, void* d_ws, size_t ws_size,
                              hipStream_t stream) {
    const float* x     = (const float*)d_in[0];
    const float* M_out = (const float*)d_in[3];
    const float* W1    = (const float*)d_in[5];
    const float* W3    = (const float*)d_in[6];
    const float* W5    = (const float*)d_in[7];
    const float* W7    = (const float*)d_in[8];
    const float* W9    = (const float*)d_in[9];
    // d_in[1]=M_first, d_in[2]=M_cn (patterns implied by check structure),
    // d_in[4]=bias_matrix (values 1.0), d_in[10..14]=B0..B4 (identity).
    float* out = (float*)d_out;

    char* ws = (char*)d_ws;                    // 16B-aligned base
    float4* w1q     = (float4*)ws;         ws += (EE / 2) * 16;
    float4* w3q     = (float4*)ws;         ws += (EE / 2) * 16;
    float4* w5q     = (float4*)ws;         ws += (EE / 2) * 16;
    float4* w7q     = (float4*)ws;         ws += (EE / 2) * 16;
    int*    var_of  = (int*)ws;            ws += EE * 4;
    int*    varEdge = (int*)ws;            ws += NN * 3 * 4;
    float*  w9v     = (float*)ws;          ws += NN * 3 * 4;
    unsigned* nb6   = (unsigned*)ws;       ws += EE * 4;
    unsigned short* varc16 = (unsigned short*)ws; ws += EE * 2;

    const int tot4 = NN * EE / 4;
    extract_struct<<<(tot4 + BS - 1) / BS, BS, 0, stream>>>(
        (const float4*)M_out, var_of, varEdge, varc16);
    const int totW = 4 * EE + NN;
    extract_weights<<<(totW + BS - 1) / BS, BS, 0, stream>>>(
        W1, W3, W5, W7, W9, var_of, varEdge, nb6, w1q, w3q, w5q, w7q, w9v);
    bp_main<<<BATCH, BSM, 0, stream>>>(
        x, (const unsigned*)varc16, nb6, varEdge, w1q, w3q, w5q, w7q, w9v, out);
}